// Round 5
// baseline (4180.592 us; speedup 1.0000x reference)
//
#include <hip/hip_runtime.h>
#include <cstdint>
#include <cmath>

#define NN   4096
#define EE   5
#define WIN  512
#define WOUT 128
#define HH0  1152   // WIN + EE*WOUT
#define NLAY 64
#define NCLS 16
#define MT   1024
#define GCAP 96     // per-(e,node) list cap; Binomial(4096,0.01) max ~70
#define BCAP 320    // per-node union cap; Binomial(4096,0.049) max ~260
#define ECAP 48     // per-(e, quarter-row) cap

typedef __attribute__((ext_vector_type(8))) short     bf16x8_t;
typedef __attribute__((ext_vector_type(8))) unsigned short ushort8_t;
typedef __attribute__((ext_vector_type(4))) float     f32x4_t;

__device__ inline unsigned short f2bf(float f) {
  unsigned int u = __float_as_uint(f);
  unsigned int r = (u + 0x7FFFu + ((u >> 16) & 1u)) >> 16;  // RNE
  return (unsigned short)r;
}
__device__ inline float bf2f(unsigned short s) {
  return __uint_as_float(((unsigned int)s) << 16);
}

// ---------------------------------------------------------------------------
// Generic register-tiled fp32 GEMM: C = act(A[M,K] @ W[K,N] + bias)
// 64x64 tile, 256 threads, 4x4 outputs/thread, BK=16. act:0=none,1=relu,2=leaky
// ---------------------------------------------------------------------------
__global__ __launch_bounds__(256) void gemm_kernel(
    const float* __restrict__ A, const float* __restrict__ W,
    const float* __restrict__ bias, float* __restrict__ C,
    int Mdim, int Kdim, int Ndim, int act) {
  __shared__ __align__(16) float sA[16][68];
  __shared__ __align__(16) float sW[16][64];
  int tid = threadIdx.x;
  int tx = tid & 15, ty = tid >> 4;
  int row0 = blockIdx.y * 64, col0 = blockIdx.x * 64;
  float acc[4][4] = {};
  int mA = tid >> 2;
  int kA = (tid & 3) << 2;
  int kW = tid >> 4;
  int nW = (tid & 15) << 2;
  for (int k0 = 0; k0 < Kdim; k0 += 16) {
    float4 av = *(const float4*)(A + (size_t)(row0 + mA) * Kdim + k0 + kA);
    float4 wv = *(const float4*)(W + (size_t)(k0 + kW) * Ndim + col0 + nW);
    sA[kA + 0][mA] = av.x;
    sA[kA + 1][mA] = av.y;
    sA[kA + 2][mA] = av.z;
    sA[kA + 3][mA] = av.w;
    *(float4*)&sW[kW][nW] = wv;
    __syncthreads();
#pragma unroll
    for (int kk = 0; kk < 16; kk++) {
      float4 a = *(const float4*)&sA[kk][ty << 2];
      float4 b = *(const float4*)&sW[kk][tx << 2];
      acc[0][0] += a.x * b.x; acc[0][1] += a.x * b.y; acc[0][2] += a.x * b.z; acc[0][3] += a.x * b.w;
      acc[1][0] += a.y * b.x; acc[1][1] += a.y * b.y; acc[1][2] += a.y * b.z; acc[1][3] += a.y * b.w;
      acc[2][0] += a.z * b.x; acc[2][1] += a.z * b.y; acc[2][2] += a.z * b.z; acc[2][3] += a.z * b.w;
      acc[3][0] += a.w * b.x; acc[3][1] += a.w * b.y; acc[3][2] += a.w * b.z; acc[3][3] += a.w * b.w;
    }
    __syncthreads();
  }
#pragma unroll
  for (int i = 0; i < 4; i++) {
    int r = row0 + (ty << 2) + i;
#pragma unroll
    for (int jc = 0; jc < 4; jc++) {
      int c = col0 + (tx << 2) + jc;
      float o = acc[i][jc];
      if (bias) o += bias[c];
      if (act == 1) o = fmaxf(o, 0.f);
      else if (act == 2) o = (o >= 0.f) ? o : 0.01f * o;
      C[(size_t)r * Ndim + c] = o;
    }
  }
}

// ---------------------------------------------------------------------------
// Forward scan: block = quarter-row, coalesced list build.
// ---------------------------------------------------------------------------
__global__ __launch_bounds__(256) void scan_rows_kernel(
    const float* __restrict__ A, int* __restrict__ fcnt, int* __restrict__ fidx,
    float* __restrict__ fval, int* __restrict__ bcnt, int* __restrict__ bidx) {
  __shared__ int   lbuf[1024];
  __shared__ int   lcnt;
  __shared__ int   ecnt[EE];
  __shared__ int   en2[EE][ECAP];
  __shared__ float ev[EE][ECAP];
  __shared__ int   rbase;
  __shared__ int   gbase[EE];
  int tid = threadIdx.x;
  int n1 = blockIdx.x >> 2;
  int qb = (blockIdx.x & 3) << 10;
  if (tid == 0) lcnt = 0;
  if (tid < EE) ecnt[tid] = 0;
  __syncthreads();
  const float4* src = (const float4*)(A + ((size_t)n1 * NN + qb) * EE);
  float buf[20];
  float4* bf4 = (float4*)buf;
#pragma unroll
  for (int c = 0; c < 5; c++) bf4[c] = src[tid * 5 + c];
  int n2base = qb + tid * 4;
#pragma unroll
  for (int u = 0; u < 4; u++) {
    int n2 = n2base + u;
    if (n2 == n1) continue;
    bool any = false;
#pragma unroll
    for (int e = 0; e < EE; e++) {
      float v = buf[u * 5 + e];
      if (v != 0.f) {
        any = true;
        int s = atomicAdd(&ecnt[e], 1);
        if (s < ECAP) { en2[e][s] = n2; ev[e][s] = v; }
      }
    }
    if (any) {
      int s = atomicAdd(&lcnt, 1);
      lbuf[s] = n2;
    }
  }
  __syncthreads();
  if (tid == 0) rbase = atomicAdd(&bcnt[n1], lcnt);
  if (tid < EE) gbase[tid] = atomicAdd(&fcnt[tid * NN + n1], min(ecnt[tid], ECAP));
  __syncthreads();
  int c = lcnt, rb = rbase;
  for (int s = tid; s < c; s += 256)
    if (rb + s < BCAP) bidx[(size_t)n1 * BCAP + rb + s] = lbuf[s];
#pragma unroll
  for (int e = 0; e < EE; e++) {
    int ec = min(ecnt[e], ECAP), gb = gbase[e];
    size_t base = ((size_t)e * NN + n1) * GCAP;
    for (int s = tid; s < ec; s += 256) {
      if (gb + s < GCAP) {
        fidx[base + gb + s] = en2[e][s];
        fval[base + gb + s] = ev[e][s];
      }
    }
  }
}

// Forward -> transposed gcn lists (for lgcn).
__global__ __launch_bounds__(64) void transpose_kernel(
    const int* __restrict__ fcnt, const int* __restrict__ fidx, const float* __restrict__ fval,
    int* __restrict__ gcnt, int* __restrict__ gidx, float* __restrict__ gval) {
  int id = blockIdx.x;                      // e*NN + n1
  int n1 = id & (NN - 1);
  int e  = id >> 12;
  int c = min(fcnt[id], GCAP);
  for (int s = threadIdx.x; s < c; s += 64) {
    int   n2 = fidx[(size_t)id * GCAP + s];
    float v  = fval[(size_t)id * GCAP + s];
    int t = e * NN + n2;
    int slot = atomicAdd(&gcnt[t], 1);
    if (slot < GCAP) {
      gidx[(size_t)t * GCAP + slot] = n1;
      gval[(size_t)t * GCAP + slot] = v;
    }
  }
}

// dinv[e,i] = 1/(1 + sum gval)   ;   dis[i] = rsqrt(1 + bcnt[i])
__global__ void dinv_dis_kernel(const int* __restrict__ gcnt, const float* __restrict__ gval,
                                float* __restrict__ dinv, const int* __restrict__ bcnt,
                                float* __restrict__ dis) {
  int t = blockIdx.x * 256 + threadIdx.x;
  if (t < EE * NN) {
    int cnt = min(gcnt[t], GCAP);
    float s = 1.0f;
    for (int k = 0; k < cnt; k++) s += gval[(size_t)t * GCAP + k];
    dinv[t] = 1.0f / s;
  }
  if (t < NN) dis[t] = rsqrtf(1.0f + (float)min(bcnt[t], BCAP));
}

// ---------------------------------------------------------------------------
// Dense A_hat bf16 build (row-major, k-contig).
// ---------------------------------------------------------------------------
__global__ __launch_bounds__(256) void build_ahat_kernel(
    const int* __restrict__ bcnt, const int* __restrict__ bidx,
    const float* __restrict__ dis, unsigned short* __restrict__ Ab) {
  __shared__ unsigned int bits[128];
  int i = blockIdx.x, t = threadIdx.x;
  if (t < 128) bits[t] = 0;
  __syncthreads();
  int cnt = min(bcnt[i], BCAP);
  for (int s = t; s < cnt; s += 256) {
    int j = bidx[(size_t)i * BCAP + s];
    atomicOr(&bits[j >> 5], 1u << (j & 31));
  }
  __syncthreads();
  float di = dis[i];
  int c0 = t * 16;
  unsigned short out[16];
#pragma unroll
  for (int u = 0; u < 16; u++) {
    int j = c0 + u;
    bool on = ((bits[j >> 5] >> (j & 31)) & 1u) || (j == i);
    out[u] = on ? f2bf(di * dis[j]) : (unsigned short)0;
  }
  *(ushort8_t*)&Ab[(size_t)i * NN + c0]     = *(ushort8_t*)&out[0];
  *(ushort8_t*)&Ab[(size_t)i * NN + c0 + 8] = *(ushort8_t*)&out[8];
}

// Wconvs fp32 [l][k][n] -> WbT bf16 [l][n][k]  (one-time)
__global__ __launch_bounds__(256) void wconv_kernel(const float* __restrict__ W,
                                                    unsigned short* __restrict__ WbT) {
  int l = blockIdx.x;
  const float* Wl = W + (size_t)l * WOUT * WOUT;
  unsigned short* o = WbT + (size_t)l * WOUT * WOUT;
  for (int idx = threadIdx.x; idx < WOUT * WOUT; idx += 256) {
    int n = idx & 127, k = idx >> 7;        // lanes consecutive in n: coalesced read
    o[(size_t)n * WOUT + k] = f2bf(Wl[(size_t)k * WOUT + n]);
  }
}

// lgcn[e,i,d] = relu( dinv[e,i] * (Xw[i,d] + sum_s v_s * Xw[j_s,d]) )
__global__ __launch_bounds__(128) void lgcn_kernel(
    const int* __restrict__ gcnt, const int* __restrict__ gidx, const float* __restrict__ gval,
    const float* __restrict__ dinv, const float* __restrict__ Xw, float* __restrict__ lgcn) {
  int i = blockIdx.x, e = blockIdx.y, d = threadIdx.x;
  int t = e * NN + i;
  int cnt = min(gcnt[t], GCAP);
  __shared__ int   sj[GCAP];
  __shared__ float sv[GCAP];
  for (int s = d; s < cnt; s += 128) {
    sj[s] = gidx[(size_t)t * GCAP + s];
    sv[s] = gval[(size_t)t * GCAP + s];
  }
  __syncthreads();
  float acc = Xw[(size_t)i * WOUT + d];
  for (int s = 0; s < cnt; s++) acc += sv[s] * Xw[(size_t)sj[s] * WOUT + d];
  float r = dinv[t] * acc;
  lgcn[(size_t)t * WOUT + d] = fmaxf(r, 0.f);
}

__global__ void att_partial_kernel(const float* __restrict__ lgcn, const float* __restrict__ attw,
                                   float* __restrict__ tm_pre) {
  int e = blockIdx.y, d = threadIdx.x;
  int nbase = blockIdx.x * 128;
  float acc = 0.f;
  for (int k = 0; k < 128; k++) {
    int n = nbase + k;
    acc += attw[n] * lgcn[((size_t)(e * NN + n)) * WOUT + d];
  }
  atomicAdd(&tm_pre[e * WOUT + d], acc);
}

__global__ void att_final_kernel(const float* __restrict__ tm_pre, const float* __restrict__ attb,
                                 const float* __restrict__ attq, float* __restrict__ beta) {
  int lane = threadIdx.x;  // 64
  __shared__ float sw[EE];
  for (int e = 0; e < EE; e++) {
    float v = 0.f;
    for (int d = lane; d < WOUT; d += 64) {
      float tmv = tanhf(tm_pre[e * WOUT + d] + attb[d]);
      v += tmv * attq[d];
    }
    for (int off = 32; off; off >>= 1) v += __shfl_down(v, off, 64);
    if (lane == 0) sw[e] = v;
  }
  __syncthreads();
  if (lane == 0) {
    float mx = sw[0];
    for (int e = 1; e < EE; e++) mx = fmaxf(mx, sw[e]);
    float se = 0.f, ex[EE];
    for (int e = 0; e < EE; e++) { ex[e] = expf(sw[e] - mx); se += ex[e]; }
    for (int e = 0; e < EE; e++) beta[e] = ex[e] / se * (float)EE;
  }
}

__global__ void xcat_kernel(const float* __restrict__ lgcn, const float* __restrict__ X,
                            const float* __restrict__ beta, float* __restrict__ Xc) {
  int idx = blockIdx.x * 256 + threadIdx.x;
  const int total = NN * HH0;
  for (; idx < total; idx += gridDim.x * 256) {
    int n = idx / HH0, c = idx - n * HH0;
    float v;
    if (c < EE * WOUT) {
      int e = c >> 7, d = c & 127;
      v = beta[e] * lgcn[((size_t)(e * NN + n)) * WOUT + d];
    } else {
      v = X[(size_t)n * WIN + (c - EE * WOUT)];
    }
    Xc[idx] = v;
  }
}

// x (fp32 [NN][128]) -> xT (bf16 [128][NN]) via LDS transpose. 32 rows/block.
__global__ __launch_bounds__(256) void xT_convert_kernel(
    const float* __restrict__ x, unsigned short* __restrict__ xT) {
  __shared__ float sh2[128][36];    // [c][r]
  int r0 = blockIdx.x * 32, t = threadIdx.x;
  const float4* x4 = (const float4*)(x + (size_t)r0 * WOUT);
#pragma unroll
  for (int q = 0; q < 4; q++) {
    int lin = t + q * 256;
    int r = lin >> 5, c = (lin & 31) * 4;
    float4 v = x4[lin];
    sh2[c + 0][r] = v.x; sh2[c + 1][r] = v.y; sh2[c + 2][r] = v.z; sh2[c + 3][r] = v.w;
  }
  __syncthreads();
  int c = t >> 1, half = t & 1;
  unsigned short tmp[16];
#pragma unroll
  for (int rr = 0; rr < 16; rr++) tmp[rr] = f2bf(sh2[c][half * 16 + rr]);
  *(ushort8_t*)&xT[(size_t)c * NN + r0 + half * 16]     = *(ushort8_t*)&tmp[0];
  *(ushort8_t*)&xT[(size_t)c * NN + r0 + half * 16 + 8] = *(ushort8_t*)&tmp[8];
}

// ---------------------------------------------------------------------------
// FUSED GCNII layer. Grid 256 blocks x 256 threads. Block = 16-row M-tile x
// full N=128 x full K=4096. K-loop: direct global->MFMA (no LDS, no barriers);
// af (A_hat rows) identical across the 4 waves -> L1-served. Epilogue in-kernel:
// h' = 0.9S + 0.1 x0 -> bf16 LDS A-frag -> MFMA h'@WlT -> relu -> LDS
// transpose -> coalesced bf16 xT emit (+ fp32 rows on last layer).
// Frag layouts identical to R4's verified spmm (A[m=l15][k=quad*8+j];
// B as [n=l15][k]; D col=l15,row=quad*4+r).
// ---------------------------------------------------------------------------
__global__ __launch_bounds__(256) void gcnii_fused_kernel(
    const unsigned short* __restrict__ Ab, const unsigned short* __restrict__ xT,
    const float* __restrict__ x0, const unsigned short* __restrict__ WbT,
    float bl, unsigned short* __restrict__ yT, float* __restrict__ yf32,
    int write_f32) {
  __shared__ __align__(16) unsigned short sh_h[16 * 136];   // h' bf16 [row][k], stride 136 (16B-aligned rows, 2-way banks)
  __shared__ __align__(16) unsigned short sh_y[128 * 24];   // y bf16 [col][row], stride 24 (16B-aligned)
  int t = threadIdx.x;
  int wave = t >> 6, lane = t & 63;
  int quad = lane >> 4, l15 = lane & 15;
  int r0 = blockIdx.x * 16;
  int c0 = wave * 32;                       // wave covers cols c0..c0+31
  int colA = c0 + l15, colB = c0 + 16 + l15;

  f32x4_t acc0 = {0.f, 0.f, 0.f, 0.f}, acc1 = {0.f, 0.f, 0.f, 0.f};
  const unsigned short* ap  = Ab + (size_t)(r0 + l15) * NN + quad * 8;
  const unsigned short* bp0 = xT + (size_t)colA * NN + quad * 8;
  const unsigned short* bp1 = xT + (size_t)colB * NN + quad * 8;
#pragma unroll 4
  for (int k = 0; k < NN; k += 32) {
    bf16x8_t a  = *(const bf16x8_t*)(ap + k);
    bf16x8_t b0 = *(const bf16x8_t*)(bp0 + k);
    bf16x8_t b1 = *(const bf16x8_t*)(bp1 + k);
    acc0 = __builtin_amdgcn_mfma_f32_16x16x32_bf16(a, b0, acc0, 0, 0, 0);
    acc1 = __builtin_amdgcn_mfma_f32_16x16x32_bf16(a, b1, acc1, 0, 0, 0);
  }

  // h' = 0.9*S + 0.1*x0 -> sh_h (bf16)
#pragma unroll
  for (int r = 0; r < 4; r++) {
    int row = quad * 4 + r;
    float h0 = 0.9f * acc0[r] + 0.1f * x0[(size_t)(r0 + row) * WOUT + colA];
    float h1 = 0.9f * acc1[r] + 0.1f * x0[(size_t)(r0 + row) * WOUT + colB];
    sh_h[row * 136 + colA] = f2bf(h0);
    sh_h[row * 136 + colB] = f2bf(h1);
  }
  __syncthreads();

  // o = h' @ Wl  (A-frag from sh_h, B-frag from WbT[n][k] global)
  f32x4_t o0 = {0.f, 0.f, 0.f, 0.f}, o1 = {0.f, 0.f, 0.f, 0.f};
#pragma unroll
  for (int kst = 0; kst < 4; kst++) {
    bf16x8_t ah = *(const bf16x8_t*)&sh_h[l15 * 136 + kst * 32 + quad * 8];
    bf16x8_t w0 = *(const bf16x8_t*)&WbT[(size_t)colA * WOUT + kst * 32 + quad * 8];
    bf16x8_t w1 = *(const bf16x8_t*)&WbT[(size_t)colB * WOUT + kst * 32 + quad * 8];
    o0 = __builtin_amdgcn_mfma_f32_16x16x32_bf16(ah, w0, o0, 0, 0, 0);
    o1 = __builtin_amdgcn_mfma_f32_16x16x32_bf16(ah, w1, o1, 0, 0, 0);
  }

  float c1 = 1.f - bl;
#pragma unroll
  for (int r = 0; r < 4; r++) {
    int row = quad * 4 + r;
    float hA = bf2f(sh_h[row * 136 + colA]);
    float hB = bf2f(sh_h[row * 136 + colB]);
    float yA = fmaxf(c1 * hA + bl * o0[r], 0.f);
    float yB = fmaxf(c1 * hB + bl * o1[r], 0.f);
    sh_y[colA * 24 + row] = f2bf(yA);
    sh_y[colB * 24 + row] = f2bf(yB);
    if (write_f32) {
      yf32[(size_t)(r0 + row) * WOUT + colA] = yA;
      yf32[(size_t)(r0 + row) * WOUT + colB] = yB;
    }
  }
  __syncthreads();

  // coalesced bf16 xT emit: thread t -> col t>>1, 8 rows
  int col = t >> 1, r8 = (t & 1) * 8;
  ushort8_t v = *(const ushort8_t*)&sh_y[col * 24 + r8];
  *(ushort8_t*)&yT[(size_t)col * NN + r0 + r8] = v;
}

// y = Z[tx]@W2 + b2 ; per-row log-softmax ; per-block loss partials
__global__ __launch_bounds__(256) void head_kernel(
    const float* __restrict__ Z, const int* __restrict__ txv, const int* __restrict__ tgt,
    const float* __restrict__ W2, const float* __restrict__ b2,
    float* __restrict__ out_y, float* __restrict__ lossp) {
  int tid = threadIdx.x;
  int mr = tid >> 4, c = tid & 15;
  int m = blockIdx.x * 16 + mr;
  const float* zr = Z + (size_t)txv[m] * WOUT;
  float acc = b2[c];
  for (int k = 0; k < WOUT; k++) acc += zr[k] * W2[k * NCLS + c];
  out_y[(size_t)m * NCLS + c] = acc;
  float mx = acc;
  for (int off = 8; off; off >>= 1) mx = fmaxf(mx, __shfl_xor(mx, off, 16));
  float ex = expf(acc - mx);
  float se = ex;
  for (int off = 8; off; off >>= 1) se += __shfl_xor(se, off, 16);
  float lse = mx + logf(se);
  float contrib = (c == tgt[m]) ? (lse - acc) : 0.f;
  __shared__ float red[256];
  red[tid] = contrib;
  __syncthreads();
  for (int stp = 128; stp; stp >>= 1) {
    if (tid < stp) red[tid] += red[tid + stp];
    __syncthreads();
  }
  if (tid == 0) lossp[blockIdx.x] = red[0];
}

__global__ void loss_final_kernel(const float* __restrict__ lossp, float* __restrict__ out_loss) {
  int lane = threadIdx.x;
  float v = (lane < 64) ? lossp[lane] : 0.f;
  for (int off = 32; off; off >>= 1) v += __shfl_down(v, off, 64);
  if (lane == 0) out_loss[0] = v / (float)MT;
}

// ---------------------------------------------------------------------------
extern "C" void kernel_launch(void* const* d_in, const int* in_sizes, int n_in,
                              void* d_out, int out_size, void* d_ws, size_t ws_size,
                              hipStream_t stream) {
  const float* A      = (const float*)d_in[0];
  const float* X      = (const float*)d_in[1];
  const int*   txv    = (const int*)d_in[2];
  const int*   tgt    = (const int*)d_in[3];
  const float* weight = (const float*)d_in[4];
  const float* attw   = (const float*)d_in[5];
  const float* attb   = (const float*)d_in[6];
  const float* attq   = (const float*)d_in[7];
  const float* Wg     = (const float*)d_in[8];
  const float* bg     = (const float*)d_in[9];
  const float* W0     = (const float*)d_in[10];
  const float* b0     = (const float*)d_in[11];
  const float* Wconvs = (const float*)d_in[12];
  const float* Wd1    = (const float*)d_in[13];
  const float* bd1    = (const float*)d_in[14];
  const float* W1     = (const float*)d_in[15];
  const float* b1     = (const float*)d_in[16];
  const float* W2     = (const float*)d_in[17];
  const float* b2     = (const float*)d_in[18];

  float* ws  = (float*)d_ws;
  int*   wsi = (int*)d_ws;

  // offsets in 4-byte units
  const size_t O_GCNT  = 0;                         // 20480 ints
  const size_t O_BCNT  = 20480;                     // 4096
  const size_t O_FCNT  = 24576;                     // 20480
  const size_t O_DINV  = 45056;                     // 20480
  const size_t O_DIS   = 65536;                     // 4096
  const size_t O_TMPRE = 69632;                     // 640
  const size_t O_BETA  = 70272;                     // 16
  const size_t O_LOSSP = 70288;                     // 64
  const size_t O_GIDX  = 71680;                     // 1966080
  const size_t O_GVAL  = O_GIDX + 1966080;
  const size_t O_FIDX  = O_GVAL + 1966080;
  const size_t O_FVAL  = O_FIDX + 1966080;
  const size_t O_BIDX  = O_FVAL + 1966080;          // 1310720
  const size_t O_LGCN  = O_BIDX + 1310720;          // 2621440
  const size_t O_XW    = O_LGCN + 2621440;          // 524288
  const size_t O_X0    = O_XW   + 524288;           // 524288
  const size_t O_XA    = O_X0   + 524288;           // 524288
  const size_t O_XB    = O_XA   + 524288;           // 524288
  const size_t O_AB    = O_XB   + 524288;           // 8388608 (4096x4096 bf16)
  const size_t O_XBT0  = O_AB   + 8388608;          // 262144  (128x4096 bf16)
  const size_t O_XBT1  = O_XBT0 + 262144;           // 262144
  const size_t O_WBT   = O_XBT1 + 262144;           // 524288  (64x128x128 bf16)
  // aliases (lifetimes verified by launch order):
  const size_t O_T1    = O_FVAL;   // [4096,512] dead before scan writes fval/bidx
  const size_t O_XCAT  = O_GIDX;   // [4096,1152] built after gidx/gval/fidx last reads

  hipMemsetAsync(ws + O_GCNT, 0, 45056 * 4, stream);   // gcnt+bcnt+fcnt
  hipMemsetAsync(ws + O_TMPRE, 0, 640 * 4, stream);

  dim3 blk(256);
  // Stage A: Xw = leaky(leaky(X@Wg+bg)@weight)
  gemm_kernel<<<dim3(WIN / 64, NN / 64), blk, 0, stream>>>(X, Wg, bg, ws + O_T1, NN, WIN, WIN, 2);
  gemm_kernel<<<dim3(WOUT / 64, NN / 64), blk, 0, stream>>>(ws + O_T1, weight, nullptr, ws + O_XW, NN, WIN, WOUT, 2);
  // Stage B: sparse structures + dense A_hat + bf16 weights
  scan_rows_kernel<<<NN * 4, 256, 0, stream>>>(A, wsi + O_FCNT, wsi + O_FIDX, ws + O_FVAL,
                                               wsi + O_BCNT, wsi + O_BIDX);
  transpose_kernel<<<EE * NN, 64, 0, stream>>>(wsi + O_FCNT, wsi + O_FIDX, ws + O_FVAL,
                                               wsi + O_GCNT, wsi + O_GIDX, ws + O_GVAL);
  dinv_dis_kernel<<<80, 256, 0, stream>>>(wsi + O_GCNT, ws + O_GVAL, ws + O_DINV,
                                          wsi + O_BCNT, ws + O_DIS);
  build_ahat_kernel<<<NN, 256, 0, stream>>>(wsi + O_BCNT, wsi + O_BIDX, ws + O_DIS,
                                            (unsigned short*)(ws + O_AB));
  wconv_kernel<<<NLAY, 256, 0, stream>>>(Wconvs, (unsigned short*)(ws + O_WBT));
  // Stage C: lgcn
  lgcn_kernel<<<dim3(NN, EE), 128, 0, stream>>>(wsi + O_GCNT, wsi + O_GIDX, ws + O_GVAL,
                                                ws + O_DINV, ws + O_XW, ws + O_LGCN);
  // Stage D: attention -> beta
  att_partial_kernel<<<dim3(32, EE), 128, 0, stream>>>(ws + O_LGCN, attw, ws + O_TMPRE);
  att_final_kernel<<<1, 64, 0, stream>>>(ws + O_TMPRE, attb, attq, ws + O_BETA);
  // Stage E: X_ and x0
  xcat_kernel<<<4096, 256, 0, stream>>>(ws + O_LGCN, X, ws + O_BETA, ws + O_XCAT);
  gemm_kernel<<<dim3(WOUT / 64, NN / 64), blk, 0, stream>>>(ws + O_XCAT, W0, b0, ws + O_X0, NN, HH0, WOUT, 1);
  xT_convert_kernel<<<NN / 32, 256, 0, stream>>>(ws + O_X0, (unsigned short*)(ws + O_XBT0));
  // Stage F: 64 fused GCNII layers (one kernel each)
  for (int l = 0; l < NLAY; l++) {
    float bl = logf(0.5f / (float)(l + 1) + 1.0f);
    const unsigned short* xin = (const unsigned short*)(ws + ((l & 1) ? O_XBT1 : O_XBT0));
    unsigned short* xoT = (unsigned short*)(ws + ((l & 1) ? O_XBT0 : O_XBT1));
    gcnii_fused_kernel<<<NN / 16, 256, 0, stream>>>(
        (const unsigned short*)(ws + O_AB), xin, ws + O_X0,
        (const unsigned short*)(ws + O_WBT) + (size_t)l * WOUT * WOUT,
        bl, xoT, ws + O_XA, (l == NLAY - 1) ? 1 : 0);
  }
  // Stage G: head (fp32 x in O_XA)
  gemm_kernel<<<dim3(WOUT / 64, NN / 64), blk, 0, stream>>>(ws + O_XA, Wd1, bd1, ws + O_XB, NN, WOUT, WOUT, 2);
  gemm_kernel<<<dim3(WOUT / 64, NN / 64), blk, 0, stream>>>(ws + O_XB, W1, b1, ws + O_X0, NN, WOUT, WOUT, 2);
  head_kernel<<<MT / 16, 256, 0, stream>>>(ws + O_X0, txv, tgt, W2, b2,
                                           (float*)d_out + 1, ws + O_LOSSP);
  loss_final_kernel<<<1, 64, 0, stream>>>(ws + O_LOSSP, (float*)d_out);
}

// Round 6
// 3302.074 us; speedup vs baseline: 1.2661x; 1.2661x over previous
//
#include <hip/hip_runtime.h>
#include <cstdint>
#include <cmath>

#define NN   4096
#define NNP  4128   // padded k-stride (bf16 matrices) to spread L2 channels
#define EE   5
#define WIN  512
#define WOUT 128
#define HH0  1152   // WIN + EE*WOUT
#define NLAY 64
#define NCLS 16
#define MT   1024
#define GCAP 96     // per-(e,node) list cap; Binomial(4096,0.01) max ~70
#define BCAP 320    // per-node union cap; Binomial(4096,0.049) max ~260
#define ECAP 48     // per-(e, quarter-row) cap
#define KC   128    // K-chunk staged in LDS per iteration
#define XSTR 152    // LDS col stride (els): byte-shift 304/4=76 ≡ 12 mod 32 (2-4 way max)

typedef __attribute__((ext_vector_type(8))) short     bf16x8_t;
typedef __attribute__((ext_vector_type(8))) unsigned short ushort8_t;
typedef __attribute__((ext_vector_type(4))) float     f32x4_t;

__device__ inline unsigned short f2bf(float f) {
  unsigned int u = __float_as_uint(f);
  unsigned int r = (u + 0x7FFFu + ((u >> 16) & 1u)) >> 16;  // RNE
  return (unsigned short)r;
}
__device__ inline float bf2f(unsigned short s) {
  return __uint_as_float(((unsigned int)s) << 16);
}

// ---------------------------------------------------------------------------
// Generic register-tiled fp32 GEMM: C = act(A[M,K] @ W[K,N] + bias)
// ---------------------------------------------------------------------------
__global__ __launch_bounds__(256) void gemm_kernel(
    const float* __restrict__ A, const float* __restrict__ W,
    const float* __restrict__ bias, float* __restrict__ C,
    int Mdim, int Kdim, int Ndim, int act) {
  __shared__ __align__(16) float sA[16][68];
  __shared__ __align__(16) float sW[16][64];
  int tid = threadIdx.x;
  int tx = tid & 15, ty = tid >> 4;
  int row0 = blockIdx.y * 64, col0 = blockIdx.x * 64;
  float acc[4][4] = {};
  int mA = tid >> 2;
  int kA = (tid & 3) << 2;
  int kW = tid >> 4;
  int nW = (tid & 15) << 2;
  for (int k0 = 0; k0 < Kdim; k0 += 16) {
    float4 av = *(const float4*)(A + (size_t)(row0 + mA) * Kdim + k0 + kA);
    float4 wv = *(const float4*)(W + (size_t)(k0 + kW) * Ndim + col0 + nW);
    sA[kA + 0][mA] = av.x;
    sA[kA + 1][mA] = av.y;
    sA[kA + 2][mA] = av.z;
    sA[kA + 3][mA] = av.w;
    *(float4*)&sW[kW][nW] = wv;
    __syncthreads();
#pragma unroll
    for (int kk = 0; kk < 16; kk++) {
      float4 a = *(const float4*)&sA[kk][ty << 2];
      float4 b = *(const float4*)&sW[kk][tx << 2];
      acc[0][0] += a.x * b.x; acc[0][1] += a.x * b.y; acc[0][2] += a.x * b.z; acc[0][3] += a.x * b.w;
      acc[1][0] += a.y * b.x; acc[1][1] += a.y * b.y; acc[1][2] += a.y * b.z; acc[1][3] += a.y * b.w;
      acc[2][0] += a.z * b.x; acc[2][1] += a.z * b.y; acc[2][2] += a.z * b.z; acc[2][3] += a.z * b.w;
      acc[3][0] += a.w * b.x; acc[3][1] += a.w * b.y; acc[3][2] += a.w * b.z; acc[3][3] += a.w * b.w;
    }
    __syncthreads();
  }
#pragma unroll
  for (int i = 0; i < 4; i++) {
    int r = row0 + (ty << 2) + i;
#pragma unroll
    for (int jc = 0; jc < 4; jc++) {
      int c = col0 + (tx << 2) + jc;
      float o = acc[i][jc];
      if (bias) o += bias[c];
      if (act == 1) o = fmaxf(o, 0.f);
      else if (act == 2) o = (o >= 0.f) ? o : 0.01f * o;
      C[(size_t)r * Ndim + c] = o;
    }
  }
}

// ---------------------------------------------------------------------------
// Forward scan: block = quarter-row, coalesced list build.
// ---------------------------------------------------------------------------
__global__ __launch_bounds__(256) void scan_rows_kernel(
    const float* __restrict__ A, int* __restrict__ fcnt, int* __restrict__ fidx,
    float* __restrict__ fval, int* __restrict__ bcnt, int* __restrict__ bidx) {
  __shared__ int   lbuf[1024];
  __shared__ int   lcnt;
  __shared__ int   ecnt[EE];
  __shared__ int   en2[EE][ECAP];
  __shared__ float ev[EE][ECAP];
  __shared__ int   rbase;
  __shared__ int   gbase[EE];
  int tid = threadIdx.x;
  int n1 = blockIdx.x >> 2;
  int qb = (blockIdx.x & 3) << 10;
  if (tid == 0) lcnt = 0;
  if (tid < EE) ecnt[tid] = 0;
  __syncthreads();
  const float4* src = (const float4*)(A + ((size_t)n1 * NN + qb) * EE);
  float buf[20];
  float4* bf4 = (float4*)buf;
#pragma unroll
  for (int c = 0; c < 5; c++) bf4[c] = src[tid * 5 + c];
  int n2base = qb + tid * 4;
#pragma unroll
  for (int u = 0; u < 4; u++) {
    int n2 = n2base + u;
    if (n2 == n1) continue;
    bool any = false;
#pragma unroll
    for (int e = 0; e < EE; e++) {
      float v = buf[u * 5 + e];
      if (v != 0.f) {
        any = true;
        int s = atomicAdd(&ecnt[e], 1);
        if (s < ECAP) { en2[e][s] = n2; ev[e][s] = v; }
      }
    }
    if (any) {
      int s = atomicAdd(&lcnt, 1);
      lbuf[s] = n2;
    }
  }
  __syncthreads();
  if (tid == 0) rbase = atomicAdd(&bcnt[n1], lcnt);
  if (tid < EE) gbase[tid] = atomicAdd(&fcnt[tid * NN + n1], min(ecnt[tid], ECAP));
  __syncthreads();
  int c = lcnt, rb = rbase;
  for (int s = tid; s < c; s += 256)
    if (rb + s < BCAP) bidx[(size_t)n1 * BCAP + rb + s] = lbuf[s];
#pragma unroll
  for (int e = 0; e < EE; e++) {
    int ec = min(ecnt[e], ECAP), gb = gbase[e];
    size_t base = ((size_t)e * NN + n1) * GCAP;
    for (int s = tid; s < ec; s += 256) {
      if (gb + s < GCAP) {
        fidx[base + gb + s] = en2[e][s];
        fval[base + gb + s] = ev[e][s];
      }
    }
  }
}

// Forward -> transposed gcn lists (for lgcn).
__global__ __launch_bounds__(64) void transpose_kernel(
    const int* __restrict__ fcnt, const int* __restrict__ fidx, const float* __restrict__ fval,
    int* __restrict__ gcnt, int* __restrict__ gidx, float* __restrict__ gval) {
  int id = blockIdx.x;                      // e*NN + n1
  int n1 = id & (NN - 1);
  int e  = id >> 12;
  int c = min(fcnt[id], GCAP);
  for (int s = threadIdx.x; s < c; s += 64) {
    int   n2 = fidx[(size_t)id * GCAP + s];
    float v  = fval[(size_t)id * GCAP + s];
    int t = e * NN + n2;
    int slot = atomicAdd(&gcnt[t], 1);
    if (slot < GCAP) {
      gidx[(size_t)t * GCAP + slot] = n1;
      gval[(size_t)t * GCAP + slot] = v;
    }
  }
}

// dinv[e,i] = 1/(1 + sum gval)   ;   dis[i] = rsqrt(1 + bcnt[i])
__global__ void dinv_dis_kernel(const int* __restrict__ gcnt, const float* __restrict__ gval,
                                float* __restrict__ dinv, const int* __restrict__ bcnt,
                                float* __restrict__ dis) {
  int t = blockIdx.x * 256 + threadIdx.x;
  if (t < EE * NN) {
    int cnt = min(gcnt[t], GCAP);
    float s = 1.0f;
    for (int k = 0; k < cnt; k++) s += gval[(size_t)t * GCAP + k];
    dinv[t] = 1.0f / s;
  }
  if (t < NN) dis[t] = rsqrtf(1.0f + (float)min(bcnt[t], BCAP));
}

// ---------------------------------------------------------------------------
// Dense A_hat bf16 build (row-major, k-contig, PADDED stride NNP).
// ---------------------------------------------------------------------------
__global__ __launch_bounds__(256) void build_ahat_kernel(
    const int* __restrict__ bcnt, const int* __restrict__ bidx,
    const float* __restrict__ dis, unsigned short* __restrict__ Ab) {
  __shared__ unsigned int bits[128];
  int i = blockIdx.x, t = threadIdx.x;
  if (t < 128) bits[t] = 0;
  __syncthreads();
  int cnt = min(bcnt[i], BCAP);
  for (int s = t; s < cnt; s += 256) {
    int j = bidx[(size_t)i * BCAP + s];
    atomicOr(&bits[j >> 5], 1u << (j & 31));
  }
  __syncthreads();
  float di = dis[i];
  int c0 = t * 16;
  unsigned short out[16];
#pragma unroll
  for (int u = 0; u < 16; u++) {
    int j = c0 + u;
    bool on = ((bits[j >> 5] >> (j & 31)) & 1u) || (j == i);
    out[u] = on ? f2bf(di * dis[j]) : (unsigned short)0;
  }
  *(ushort8_t*)&Ab[(size_t)i * NNP + c0]     = *(ushort8_t*)&out[0];
  *(ushort8_t*)&Ab[(size_t)i * NNP + c0 + 8] = *(ushort8_t*)&out[8];
}

// Wconvs fp32 [l][k][n] -> WbT bf16 [l][n][k]  (one-time)
__global__ __launch_bounds__(256) void wconv_kernel(const float* __restrict__ W,
                                                    unsigned short* __restrict__ WbT) {
  int l = blockIdx.x;
  const float* Wl = W + (size_t)l * WOUT * WOUT;
  unsigned short* o = WbT + (size_t)l * WOUT * WOUT;
  for (int idx = threadIdx.x; idx < WOUT * WOUT; idx += 256) {
    int n = idx & 127, k = idx >> 7;
    o[(size_t)n * WOUT + k] = f2bf(Wl[(size_t)k * WOUT + n]);
  }
}

// lgcn[e,i,d] = relu( dinv[e,i] * (Xw[i,d] + sum_s v_s * Xw[j_s,d]) )
__global__ __launch_bounds__(128) void lgcn_kernel(
    const int* __restrict__ gcnt, const int* __restrict__ gidx, const float* __restrict__ gval,
    const float* __restrict__ dinv, const float* __restrict__ Xw, float* __restrict__ lgcn) {
  int i = blockIdx.x, e = blockIdx.y, d = threadIdx.x;
  int t = e * NN + i;
  int cnt = min(gcnt[t], GCAP);
  __shared__ int   sj[GCAP];
  __shared__ float sv[GCAP];
  for (int s = d; s < cnt; s += 128) {
    sj[s] = gidx[(size_t)t * GCAP + s];
    sv[s] = gval[(size_t)t * GCAP + s];
  }
  __syncthreads();
  float acc = Xw[(size_t)i * WOUT + d];
  for (int s = 0; s < cnt; s++) acc += sv[s] * Xw[(size_t)sj[s] * WOUT + d];
  float r = dinv[t] * acc;
  lgcn[(size_t)t * WOUT + d] = fmaxf(r, 0.f);
}

__global__ void att_partial_kernel(const float* __restrict__ lgcn, const float* __restrict__ attw,
                                   float* __restrict__ tm_pre) {
  int e = blockIdx.y, d = threadIdx.x;
  int nbase = blockIdx.x * 128;
  float acc = 0.f;
  for (int k = 0; k < 128; k++) {
    int n = nbase + k;
    acc += attw[n] * lgcn[((size_t)(e * NN + n)) * WOUT + d];
  }
  atomicAdd(&tm_pre[e * WOUT + d], acc);
}

__global__ void att_final_kernel(const float* __restrict__ tm_pre, const float* __restrict__ attb,
                                 const float* __restrict__ attq, float* __restrict__ beta) {
  int lane = threadIdx.x;  // 64
  __shared__ float sw[EE];
  for (int e = 0; e < EE; e++) {
    float v = 0.f;
    for (int d = lane; d < WOUT; d += 64) {
      float tmv = tanhf(tm_pre[e * WOUT + d] + attb[d]);
      v += tmv * attq[d];
    }
    for (int off = 32; off; off >>= 1) v += __shfl_down(v, off, 64);
    if (lane == 0) sw[e] = v;
  }
  __syncthreads();
  if (lane == 0) {
    float mx = sw[0];
    for (int e = 1; e < EE; e++) mx = fmaxf(mx, sw[e]);
    float se = 0.f, ex[EE];
    for (int e = 0; e < EE; e++) { ex[e] = expf(sw[e] - mx); se += ex[e]; }
    for (int e = 0; e < EE; e++) beta[e] = ex[e] / se * (float)EE;
  }
}

__global__ void xcat_kernel(const float* __restrict__ lgcn, const float* __restrict__ X,
                            const float* __restrict__ beta, float* __restrict__ Xc) {
  int idx = blockIdx.x * 256 + threadIdx.x;
  const int total = NN * HH0;
  for (; idx < total; idx += gridDim.x * 256) {
    int n = idx / HH0, c = idx - n * HH0;
    float v;
    if (c < EE * WOUT) {
      int e = c >> 7, d = c & 127;
      v = beta[e] * lgcn[((size_t)(e * NN + n)) * WOUT + d];
    } else {
      v = X[(size_t)n * WIN + (c - EE * WOUT)];
    }
    Xc[idx] = v;
  }
}

// x (fp32 [NN][128]) -> xT (bf16 [128][NNP]) via LDS transpose. 32 rows/block.
__global__ __launch_bounds__(256) void xT_convert_kernel(
    const float* __restrict__ x, unsigned short* __restrict__ xT) {
  __shared__ float sh2[128][36];    // [c][r]
  int r0 = blockIdx.x * 32, t = threadIdx.x;
  const float4* x4 = (const float4*)(x + (size_t)r0 * WOUT);
#pragma unroll
  for (int q = 0; q < 4; q++) {
    int lin = t + q * 256;
    int r = lin >> 5, c = (lin & 31) * 4;
    float4 v = x4[lin];
    sh2[c + 0][r] = v.x; sh2[c + 1][r] = v.y; sh2[c + 2][r] = v.z; sh2[c + 3][r] = v.w;
  }
  __syncthreads();
  int c = t >> 1, half = t & 1;
  unsigned short tmp[16];
#pragma unroll
  for (int rr = 0; rr < 16; rr++) tmp[rr] = f2bf(sh2[c][half * 16 + rr]);
  *(ushort8_t*)&xT[(size_t)c * NNP + r0 + half * 16]     = *(ushort8_t*)&tmp[0];
  *(ushort8_t*)&xT[(size_t)c * NNP + r0 + half * 16 + 8] = *(ushort8_t*)&tmp[8];
}

// ---------------------------------------------------------------------------
// FUSED GCNII layer v2: producer/consumer waves + double-buffered LDS.
// Grid 256 x 512 thr. Block = 16 rows x 128 cols x K=4096 (no split-K).
// Waves 0-3: consumers (cols w*32..+32, frag layout verified in R4/R5).
// Waves 4-7: producers staging xT K-chunks (KC=128) into LDS, 1 chunk ahead.
// A-frags direct from padded Ab global (L1-amortized across 4 c-waves).
// Epilogue in-kernel: h'=0.9S+0.1x0 -> h'@Wl (MFMA) -> relu -> yT (+f32 last).
// ---------------------------------------------------------------------------
__global__ __launch_bounds__(512) void gcnii_fused2_kernel(
    const unsigned short* __restrict__ Abg, const unsigned short* __restrict__ xT,
    const float* __restrict__ x0, const unsigned short* __restrict__ WbT,
    float bl, unsigned short* __restrict__ yT, float* __restrict__ yf32,
    int write_f32) {
  __shared__ __align__(16) unsigned short bufs[2][128 * XSTR];   // 76 KB
  __shared__ __align__(16) unsigned short sh_h[16 * 136];
  __shared__ __align__(16) unsigned short sh_y[128 * 24];
  int t = threadIdx.x;
  int wave = t >> 6, lane = t & 63;
  int quad = lane >> 4, l15 = lane & 15;
  int r0 = blockIdx.x * 16;
  int c0 = (wave & 3) * 32;
  int colA = c0 + l15, colB = c0 + 16 + l15;
  int pt = t - 256;                     // producer thread id (valid for wave>=4)

  f32x4_t acc0 = {0.f, 0.f, 0.f, 0.f}, acc1 = {0.f, 0.f, 0.f, 0.f};
  const unsigned short* ap = Abg + (size_t)(r0 + l15) * NNP + quad * 8;

  // producers stage chunk 0
  if (wave >= 4) {
    unsigned short* dst = bufs[0];
#pragma unroll
    for (int j = 0; j < 8; j++) {
      int idx = pt + j * 256;           // 0..2047
      int col = idx >> 4, q = idx & 15;
      ushort8_t v = *(const ushort8_t*)&xT[(size_t)col * NNP + q * 8];
      *(ushort8_t*)&dst[col * XSTR + q * 8] = v;
    }
  }
  __syncthreads();

  for (int c = 0; c < NN / KC; c++) {
    if (wave >= 4) {
      if (c + 1 < NN / KC) {
        unsigned short* dst = bufs[(c + 1) & 1];
        int k0 = (c + 1) * KC;
#pragma unroll
        for (int j = 0; j < 8; j++) {
          int idx = pt + j * 256;
          int col = idx >> 4, q = idx & 15;
          ushort8_t v = *(const ushort8_t*)&xT[(size_t)col * NNP + k0 + q * 8];
          *(ushort8_t*)&dst[col * XSTR + q * 8] = v;
        }
      }
    } else {
      const unsigned short* buf = bufs[c & 1];
      int k0 = c * KC;
#pragma unroll
      for (int s = 0; s < KC / 32; s++) {
        int kk = s * 32;
        bf16x8_t a  = *(const bf16x8_t*)(ap + k0 + kk);
        bf16x8_t b0 = *(const bf16x8_t*)&buf[colA * XSTR + kk + quad * 8];
        bf16x8_t b1 = *(const bf16x8_t*)&buf[colB * XSTR + kk + quad * 8];
        acc0 = __builtin_amdgcn_mfma_f32_16x16x32_bf16(a, b0, acc0, 0, 0, 0);
        acc1 = __builtin_amdgcn_mfma_f32_16x16x32_bf16(a, b1, acc1, 0, 0, 0);
      }
    }
    __syncthreads();
  }

  // ---- epilogue ----
  if (wave < 4) {
#pragma unroll
    for (int r = 0; r < 4; r++) {
      int row = quad * 4 + r;
      float h0 = 0.9f * acc0[r] + 0.1f * x0[(size_t)(r0 + row) * WOUT + colA];
      float h1 = 0.9f * acc1[r] + 0.1f * x0[(size_t)(r0 + row) * WOUT + colB];
      sh_h[row * 136 + colA] = f2bf(h0);
      sh_h[row * 136 + colB] = f2bf(h1);
    }
  }
  __syncthreads();
  if (wave < 4) {
    f32x4_t o0 = {0.f, 0.f, 0.f, 0.f}, o1 = {0.f, 0.f, 0.f, 0.f};
#pragma unroll
    for (int kst = 0; kst < 4; kst++) {
      bf16x8_t ah = *(const bf16x8_t*)&sh_h[l15 * 136 + kst * 32 + quad * 8];
      bf16x8_t w0 = *(const bf16x8_t*)&WbT[(size_t)colA * WOUT + kst * 32 + quad * 8];
      bf16x8_t w1 = *(const bf16x8_t*)&WbT[(size_t)colB * WOUT + kst * 32 + quad * 8];
      o0 = __builtin_amdgcn_mfma_f32_16x16x32_bf16(ah, w0, o0, 0, 0, 0);
      o1 = __builtin_amdgcn_mfma_f32_16x16x32_bf16(ah, w1, o1, 0, 0, 0);
    }
    float c1 = 1.f - bl;
#pragma unroll
    for (int r = 0; r < 4; r++) {
      int row = quad * 4 + r;
      float hA = bf2f(sh_h[row * 136 + colA]);
      float hB = bf2f(sh_h[row * 136 + colB]);
      float yA = fmaxf(c1 * hA + bl * o0[r], 0.f);
      float yB = fmaxf(c1 * hB + bl * o1[r], 0.f);
      sh_y[colA * 24 + row] = f2bf(yA);
      sh_y[colB * 24 + row] = f2bf(yB);
      if (write_f32) {
        yf32[(size_t)(r0 + row) * WOUT + colA] = yA;
        yf32[(size_t)(r0 + row) * WOUT + colB] = yB;
      }
    }
  }
  __syncthreads();
  if (t < 256) {
    int col = t >> 1, r8 = (t & 1) * 8;
    ushort8_t v = *(const ushort8_t*)&sh_y[col * 24 + r8];
    *(ushort8_t*)&yT[(size_t)col * NNP + r0 + r8] = v;
  }
}

// y = Z[tx]@W2 + b2 ; per-row log-softmax ; per-block loss partials
__global__ __launch_bounds__(256) void head_kernel(
    const float* __restrict__ Z, const int* __restrict__ txv, const int* __restrict__ tgt,
    const float* __restrict__ W2, const float* __restrict__ b2,
    float* __restrict__ out_y, float* __restrict__ lossp) {
  int tid = threadIdx.x;
  int mr = tid >> 4, c = tid & 15;
  int m = blockIdx.x * 16 + mr;
  const float* zr = Z + (size_t)txv[m] * WOUT;
  float acc = b2[c];
  for (int k = 0; k < WOUT; k++) acc += zr[k] * W2[k * NCLS + c];
  out_y[(size_t)m * NCLS + c] = acc;
  float mx = acc;
  for (int off = 8; off; off >>= 1) mx = fmaxf(mx, __shfl_xor(mx, off, 16));
  float ex = expf(acc - mx);
  float se = ex;
  for (int off = 8; off; off >>= 1) se += __shfl_xor(se, off, 16);
  float lse = mx + logf(se);
  float contrib = (c == tgt[m]) ? (lse - acc) : 0.f;
  __shared__ float red[256];
  red[tid] = contrib;
  __syncthreads();
  for (int stp = 128; stp; stp >>= 1) {
    if (tid < stp) red[tid] += red[tid + stp];
    __syncthreads();
  }
  if (tid == 0) lossp[blockIdx.x] = red[0];
}

__global__ void loss_final_kernel(const float* __restrict__ lossp, float* __restrict__ out_loss) {
  int lane = threadIdx.x;
  float v = (lane < 64) ? lossp[lane] : 0.f;
  for (int off = 32; off; off >>= 1) v += __shfl_down(v, off, 64);
  if (lane == 0) out_loss[0] = v / (float)MT;
}

// ---------------------------------------------------------------------------
extern "C" void kernel_launch(void* const* d_in, const int* in_sizes, int n_in,
                              void* d_out, int out_size, void* d_ws, size_t ws_size,
                              hipStream_t stream) {
  const float* A      = (const float*)d_in[0];
  const float* X      = (const float*)d_in[1];
  const int*   txv    = (const int*)d_in[2];
  const int*   tgt    = (const int*)d_in[3];
  const float* weight = (const float*)d_in[4];
  const float* attw   = (const float*)d_in[5];
  const float* attb   = (const float*)d_in[6];
  const float* attq   = (const float*)d_in[7];
  const float* Wg     = (const float*)d_in[8];
  const float* bg     = (const float*)d_in[9];
  const float* W0     = (const float*)d_in[10];
  const float* b0     = (const float*)d_in[11];
  const float* Wconvs = (const float*)d_in[12];
  const float* Wd1    = (const float*)d_in[13];
  const float* bd1    = (const float*)d_in[14];
  const float* W1     = (const float*)d_in[15];
  const float* b1     = (const float*)d_in[16];
  const float* W2     = (const float*)d_in[17];
  const float* b2     = (const float*)d_in[18];

  float* ws  = (float*)d_ws;
  int*   wsi = (int*)d_ws;

  // offsets in 4-byte units
  const size_t O_GCNT  = 0;                         // 20480 ints
  const size_t O_BCNT  = 20480;                     // 4096
  const size_t O_FCNT  = 24576;                     // 20480
  const size_t O_DINV  = 45056;                     // 20480
  const size_t O_DIS   = 65536;                     // 4096
  const size_t O_TMPRE = 69632;                     // 640
  const size_t O_BETA  = 70272;                     // 16
  const size_t O_LOSSP = 70288;                     // 64
  const size_t O_GIDX  = 71680;                     // 1966080
  const size_t O_GVAL  = O_GIDX + 1966080;
  const size_t O_FIDX  = O_GVAL + 1966080;
  const size_t O_FVAL  = O_FIDX + 1966080;
  const size_t O_BIDX  = O_FVAL + 1966080;          // 1310720
  const size_t O_LGCN  = O_BIDX + 1310720;          // 2621440
  const size_t O_XW    = O_LGCN + 2621440;          // 524288
  const size_t O_X0    = O_XW   + 524288;           // 524288
  const size_t O_XA    = O_X0   + 524288;           // 524288
  const size_t O_XB    = O_XA   + 524288;           // 524288
  const size_t O_AB    = O_XB   + 524288;           // 4096*4128 bf16 = 8454144 f
  const size_t O_XBT0  = O_AB   + 8454144;          // 128*4128 bf16 = 264192 f
  const size_t O_XBT1  = O_XBT0 + 264192;
  const size_t O_WBT   = O_XBT1 + 264192;           // 64*128*128 bf16 = 524288 f
  // aliases (lifetimes verified by launch order):
  const size_t O_T1    = O_FVAL;   // [4096,512] dead before scan writes fval/bidx
  const size_t O_XCAT  = O_GIDX;   // [4096,1152] built after gidx/gval/fidx last reads

  hipMemsetAsync(ws + O_GCNT, 0, 45056 * 4, stream);   // gcnt+bcnt+fcnt
  hipMemsetAsync(ws + O_TMPRE, 0, 640 * 4, stream);

  dim3 blk(256);
  // Stage A: Xw = leaky(leaky(X@Wg+bg)@weight)
  gemm_kernel<<<dim3(WIN / 64, NN / 64), blk, 0, stream>>>(X, Wg, bg, ws + O_T1, NN, WIN, WIN, 2);
  gemm_kernel<<<dim3(WOUT / 64, NN / 64), blk, 0, stream>>>(ws + O_T1, weight, nullptr, ws + O_XW, NN, WIN, WOUT, 2);
  // Stage B: sparse structures + dense A_hat + bf16 weights
  scan_rows_kernel<<<NN * 4, 256, 0, stream>>>(A, wsi + O_FCNT, wsi + O_FIDX, ws + O_FVAL,
                                               wsi + O_BCNT, wsi + O_BIDX);
  transpose_kernel<<<EE * NN, 64, 0, stream>>>(wsi + O_FCNT, wsi + O_FIDX, ws + O_FVAL,
                                               wsi + O_GCNT, wsi + O_GIDX, ws + O_GVAL);
  dinv_dis_kernel<<<80, 256, 0, stream>>>(wsi + O_GCNT, ws + O_GVAL, ws + O_DINV,
                                          wsi + O_BCNT, ws + O_DIS);
  build_ahat_kernel<<<NN, 256, 0, stream>>>(wsi + O_BCNT, wsi + O_BIDX, ws + O_DIS,
                                            (unsigned short*)(ws + O_AB));
  wconv_kernel<<<NLAY, 256, 0, stream>>>(Wconvs, (unsigned short*)(ws + O_WBT));
  // Stage C: lgcn
  lgcn_kernel<<<dim3(NN, EE), 128, 0, stream>>>(wsi + O_GCNT, wsi + O_GIDX, ws + O_GVAL,
                                                ws + O_DINV, ws + O_XW, ws + O_LGCN);
  // Stage D: attention -> beta
  att_partial_kernel<<<dim3(32, EE), 128, 0, stream>>>(ws + O_LGCN, attw, ws + O_TMPRE);
  att_final_kernel<<<1, 64, 0, stream>>>(ws + O_TMPRE, attb, attq, ws + O_BETA);
  // Stage E: X_ and x0
  xcat_kernel<<<4096, 256, 0, stream>>>(ws + O_LGCN, X, ws + O_BETA, ws + O_XCAT);
  gemm_kernel<<<dim3(WOUT / 64, NN / 64), blk, 0, stream>>>(ws + O_XCAT, W0, b0, ws + O_X0, NN, HH0, WOUT, 1);
  xT_convert_kernel<<<NN / 32, 256, 0, stream>>>(ws + O_X0, (unsigned short*)(ws + O_XBT0));
  // Stage F: 64 fused GCNII layers
  for (int l = 0; l < NLAY; l++) {
    float bl = logf(0.5f / (float)(l + 1) + 1.0f);
    const unsigned short* xin = (const unsigned short*)(ws + ((l & 1) ? O_XBT1 : O_XBT0));
    unsigned short* xoT = (unsigned short*)(ws + ((l & 1) ? O_XBT0 : O_XBT1));
    gcnii_fused2_kernel<<<NN / 16, 512, 0, stream>>>(
        (const unsigned short*)(ws + O_AB), xin, ws + O_X0,
        (const unsigned short*)(ws + O_WBT) + (size_t)l * WOUT * WOUT,
        bl, xoT, ws + O_XA, (l == NLAY - 1) ? 1 : 0);
  }
  // Stage G: head (fp32 x in O_XA)
  gemm_kernel<<<dim3(WOUT / 64, NN / 64), blk, 0, stream>>>(ws + O_XA, Wd1, bd1, ws + O_XB, NN, WOUT, WOUT, 2);
  gemm_kernel<<<dim3(WOUT / 64, NN / 64), blk, 0, stream>>>(ws + O_XB, W1, b1, ws + O_X0, NN, WOUT, WOUT, 2);
  head_kernel<<<MT / 16, 256, 0, stream>>>(ws + O_X0, txv, tgt, W2, b2,
                                           (float*)d_out + 1, ws + O_LOSSP);
  loss_final_kernel<<<1, 64, 0, stream>>>(ws + O_LOSSP, (float*)d_out);
}